// Round 1
// baseline (169.755 us; speedup 1.0000x reference)
//
#include <hip/hip_runtime.h>
#include <hip/hip_fp16.h>

typedef _Float16 half8 __attribute__((ext_vector_type(8)));
typedef float f32x4 __attribute__((ext_vector_type(4)));

#define BATCH 65536
#define KD 512
#define HD 256
#define BHSZ 16777216  // BATCH * HD

// ---------------------------------------------------------------------------
// global -> LDS direct (16B per lane). LDS dest must be wave-uniform base;
// HW adds lane*16. (m97 pattern)
// ---------------------------------------------------------------------------
__device__ __forceinline__ void gload16(const _Float16* g, _Float16* lds) {
  __builtin_amdgcn_global_load_lds((const __attribute__((address_space(1))) void*)g,
                                   (__attribute__((address_space(3))) void*)lds,
                                   16, 0, 0);
}

__device__ __forceinline__ float fast_sigmoid(float z) {
  // sigma(z) = 1/(1+2^(-z*log2e)); saturates cleanly (exp2->inf => rcp->0)
  float e = __builtin_amdgcn_exp2f(-z * 1.4426950408889634f);
  return __builtin_amdgcn_rcpf(1.0f + e);
}

__device__ __forceinline__ float fast_tanh(float z) {
  // tanh(|z|) = 1 - 2/(1+2^(2|z|*log2e)); exp2->inf => rcp->0 => 1. No NaN.
  float a = __builtin_fabsf(z);
  float e = __builtin_amdgcn_exp2f(a * 2.8853900817779268f);
  float t = 1.0f - 2.0f * __builtin_amdgcn_rcpf(1.0f + e);
  return z < 0.0f ? -t : t;
}

// ---------------------------------------------------------------------------
// pack_a: A[b][k] fp16, k<256 -> x[b][k], k>=256 -> h[b][k-256]
// 8 halves per thread, fully coalesced both sides.
// grid = 65536*512/8/256 = 16384 blocks
// ---------------------------------------------------------------------------
__global__ __launch_bounds__(256) void pack_a(const float* __restrict__ x,
                                              const float* __restrict__ h,
                                              _Float16* __restrict__ A) {
  long i = (long)blockIdx.x * 256 + threadIdx.x;
  long e = i * 8;
  int b = (int)(e >> 9);
  int k = (int)(e & 511);
  const float* src = (k < 256) ? (x + (long)b * 256 + k)
                               : (h + (long)b * 256 + (k - 256));
  float4 v0 = reinterpret_cast<const float4*>(src)[0];
  float4 v1 = reinterpret_cast<const float4*>(src)[1];
  half8 o;
  o[0] = (_Float16)v0.x; o[1] = (_Float16)v0.y;
  o[2] = (_Float16)v0.z; o[3] = (_Float16)v0.w;
  o[4] = (_Float16)v1.x; o[5] = (_Float16)v1.y;
  o[6] = (_Float16)v1.z; o[7] = (_Float16)v1.w;
  *reinterpret_cast<half8*>(A + e) = o;
}

// ---------------------------------------------------------------------------
// pack_b: Bp[N'][k] fp16 (B^T, N'-major), gate-interleaved columns:
//   N' = t*64 + g*16 + j  -> logical col cl = t*16 + j, gate g (0=f,1=i,2=o,3=c)
//   k<256 -> W_g[k][cl], k>=256 -> U_g[k-256][cl]
// grid = 1024*512/256 = 2048 blocks
// ---------------------------------------------------------------------------
__global__ __launch_bounds__(256) void pack_b(
    const float* __restrict__ Wf, const float* __restrict__ Uf,
    const float* __restrict__ Wi, const float* __restrict__ Ui,
    const float* __restrict__ Wo, const float* __restrict__ Uo,
    const float* __restrict__ Wc, const float* __restrict__ Uc,
    _Float16* __restrict__ Bp) {
  int idx = blockIdx.x * 256 + threadIdx.x;  // [0, 524288)
  int k = idx & 511;
  int Np = idx >> 9;
  int g = (Np >> 4) & 3;
  int cl = ((Np >> 6) << 4) | (Np & 15);
  const float* W;
  const float* U;
  switch (g) {
    case 0: W = Wf; U = Uf; break;
    case 1: W = Wi; U = Ui; break;
    case 2: W = Wo; U = Uo; break;
    default: W = Wc; U = Uc; break;
  }
  float v = (k < 256) ? W[k * 256 + cl] : U[(k - 256) * 256 + cl];
  Bp[idx] = (_Float16)v;
}

// ---------------------------------------------------------------------------
// lstm_gemm: z = A @ Bp^T tile (128x128), fused LSTM gate epilogue.
// 4 waves, each 64 rows x 64 cols (4x4 fragments of 16x16x32 f16 MFMA).
// Wave cols = 4 gates x 16 logical cols -> gate fusion is lane-local.
// LDS staging via global_load_lds w/ source-side XOR swizzle (slot^=row&7),
// swizzled ds_read_b128 fragment loads -> ~conflict-free.
// grid = (65536/128) * (1024/128) = 4096 blocks
// ---------------------------------------------------------------------------
__global__ __launch_bounds__(256) void lstm_gemm(
    const _Float16* __restrict__ A, const _Float16* __restrict__ Bp,
    const float* __restrict__ cin,
    const float* __restrict__ bf_, const float* __restrict__ bi_,
    const float* __restrict__ bo_, const float* __restrict__ bc_,
    float* __restrict__ out) {
  __shared__ _Float16 As[128 * 64];
  __shared__ _Float16 Bs[128 * 64];

  int tid = threadIdx.x;
  int w = tid >> 6, l = tid & 63;
  int l15 = l & 15, lg = l >> 4;
  int bx = blockIdx.x;
  int bm = bx >> 3, bn = bx & 7;   // consecutive blocks share the A panel (L2)
  int wr = w >> 1, wc = w & 1;

  // Staging addresses: inst i covers rows [i*32, i*32+32), 8x16B slots per row.
  long gaOff[4], gbOff[4];
  int ldsOff[4];
#pragma unroll
  for (int i2 = 0; i2 < 4; ++i2) {
    int idx = i2 * 256 + tid;
    int row = idx >> 3, slot = idx & 7;
    int swz = slot ^ (row & 7);  // inverse-swizzle the SOURCE, LDS stays linear
    gaOff[i2] = (long)(bm * 128 + row) * 512 + swz * 8;
    gbOff[i2] = (long)(bn * 128 + row) * 512 + swz * 8;
    ldsOff[i2] = (i2 * 256 + w * 64) * 8;  // halves; wave-uniform base
  }

  f32x4 acc[4][4];
#pragma unroll
  for (int a2 = 0; a2 < 4; ++a2)
#pragma unroll
    for (int b2 = 0; b2 < 4; ++b2)
      acc[a2][b2] = (f32x4){0.f, 0.f, 0.f, 0.f};

  for (int kt = 0; kt < 8; ++kt) {
    int ko = kt * 64;
#pragma unroll
    for (int i2 = 0; i2 < 4; ++i2) {
      gload16(A + gaOff[i2] + ko, As + ldsOff[i2]);
      gload16(Bp + gbOff[i2] + ko, Bs + ldsOff[i2]);
    }
    __syncthreads();  // compiler drains vmcnt before s_barrier
#pragma unroll
    for (int kk = 0; kk < 2; ++kk) {
      half8 av[4], bv[4];
#pragma unroll
      for (int mf = 0; mf < 4; ++mf) {
        int row = wr * 64 + mf * 16 + l15;
        int swz = (kk * 4 + lg) ^ (row & 7);
        av[mf] = *reinterpret_cast<const half8*>(&As[row * 64 + swz * 8]);
      }
#pragma unroll
      for (int nf = 0; nf < 4; ++nf) {
        int row = wc * 64 + nf * 16 + l15;
        int swz = (kk * 4 + lg) ^ (row & 7);
        bv[nf] = *reinterpret_cast<const half8*>(&Bs[row * 64 + swz * 8]);
      }
#pragma unroll
      for (int mf = 0; mf < 4; ++mf)
#pragma unroll
        for (int nf = 0; nf < 4; ++nf)
          acc[mf][nf] = __builtin_amdgcn_mfma_f32_16x16x32_f16(
              av[mf], bv[nf], acc[mf][nf], 0, 0, 0);
    }
    __syncthreads();
  }

  // Epilogue: fragment nf == gate (0=f,1=i,2=o,3=c); C/D layout col=lane&15,
  // row=(lane>>4)*4+reg (m89-verified, dtype-independent).
  int t = bn * 2 + wc;
  int col = t * 16 + l15;  // logical column in [0,256)
  float vbf = bf_[col], vbi = bi_[col], vbo = bo_[col], vbc = bc_[col];
#pragma unroll
  for (int mf = 0; mf < 4; ++mf) {
#pragma unroll
    for (int r = 0; r < 4; ++r) {
      long row = (long)(bm * 128 + wr * 64 + mf * 16 + lg * 4 + r);
      float zf = acc[mf][0][r] + vbf;
      float zi = acc[mf][1][r] + vbi;
      float zo = acc[mf][2][r] + vbo;
      float zg = acc[mf][3][r] + vbc;
      float fg = fast_sigmoid(zf);
      float ig = fast_sigmoid(zi);
      float og = fast_sigmoid(zo);
      float gg = fast_tanh(zg);
      float cv = cin[row * 256 + col];
      float cn = cv * fg + gg * ig;
      float hn = og * fast_tanh(cn);
      out[row * 256 + col] = cn;
      out[BHSZ + row * 256 + col] = hn;
    }
  }
}

// ---------------------------------------------------------------------------
extern "C" void kernel_launch(void* const* d_in, const int* in_sizes, int n_in,
                              void* d_out, int out_size, void* d_ws, size_t ws_size,
                              hipStream_t stream) {
  const float* x  = (const float*)d_in[0];
  const float* c  = (const float*)d_in[1];
  const float* h  = (const float*)d_in[2];
  const float* Wi = (const float*)d_in[3];
  const float* Ui = (const float*)d_in[4];
  const float* bi = (const float*)d_in[5];
  const float* Wf = (const float*)d_in[6];
  const float* Uf = (const float*)d_in[7];
  const float* bf = (const float*)d_in[8];
  const float* Wc = (const float*)d_in[9];
  const float* Uc = (const float*)d_in[10];
  const float* bc = (const float*)d_in[11];
  const float* Wo = (const float*)d_in[12];
  const float* Uo = (const float*)d_in[13];
  const float* bo = (const float*)d_in[14];

  _Float16* A  = (_Float16*)d_ws;                                   // 64 MB
  _Float16* Bp = (_Float16*)((char*)d_ws + (size_t)BATCH * KD * 2); // 1 MB

  pack_a<<<16384, 256, 0, stream>>>(x, h, A);
  pack_b<<<2048, 256, 0, stream>>>(Wf, Uf, Wi, Ui, Wo, Uo, Wc, Uc, Bp);
  lstm_gemm<<<4096, 256, 0, stream>>>(A, Bp, c, bf, bi, bo, bc, (float*)d_out);
}